// Round 7
// baseline (970.013 us; speedup 1.0000x reference)
//
#include <hip/hip_runtime.h>
#include <hip/hip_bf16.h>

typedef __attribute__((ext_vector_type(8))) short bf16x8;
typedef __attribute__((ext_vector_type(4))) float f32x4;
typedef __attribute__((ext_vector_type(4))) unsigned short u16x4;

#define BB 4
#define SS 2048
#define DD 2048
#define HH 16
#define HDD 128
// QK buffer: [B*S][4096] bf16 (Q cols 0..2047, K cols 2048..4095), RoPE pre-applied
// Vt buffer: [B*H][128][2048] bf16 (V transposed: hd-major, s contiguous)
// Masking sentinels: finite so (masked) - (init) never yields exp2(0)=1.
#define MASKV (-30000.0f)
#define MINIT (-15000.0f)

__device__ __forceinline__ unsigned short f2bf(float f) {
  __hip_bfloat16 b = __float2bfloat16(f);
  return *reinterpret_cast<unsigned short*>(&b);
}
__device__ __forceinline__ void gl_lds16(const void* g, void* l) {
  __builtin_amdgcn_global_load_lds((const __attribute__((address_space(1))) unsigned int*)g,
                                   (__attribute__((address_space(3))) unsigned int*)l, 16, 0, 0);
}

// ---------------- fp32 -> bf16 conversion (vectorized) ----------------
__global__ __launch_bounds__(256) void convertk(const float* __restrict__ src,
                                                __hip_bfloat16* __restrict__ dst, int n4) {
  int i = blockIdx.x * 256 + threadIdx.x;
  if (i >= n4) return;
  f32x4 v = ((const f32x4*)src)[i];
  u16x4 o;
  o[0] = f2bf(v[0]); o[1] = f2bf(v[1]); o[2] = f2bf(v[2]); o[3] = f2bf(v[3]);
  ((u16x4*)dst)[i] = o;
}

// ---------------- B^T GEMM: C[m][n] = sum_k A[m][k] * Bw[n][k] ----------------
// MODE 0: epilogue -> QK buffer with fused RoPE (n<4096) or Vt (n>=4096, transposed)
// MODE 1: epilogue -> float C row-major [M][N]
template <int MODE>
__global__ __launch_bounds__(256) void gemm_bt(const __hip_bfloat16* __restrict__ A,
                                               const __hip_bfloat16* __restrict__ Bw,
                                               __hip_bfloat16* __restrict__ Cbf,
                                               __hip_bfloat16* __restrict__ Vt,
                                               float* __restrict__ Cf,
                                               const float* __restrict__ fc,
                                               const float* __restrict__ fs,
                                               const int* __restrict__ posp,
                                               int M, int N, int K) {
  __shared__ __hip_bfloat16 As[128 * 32];
  __shared__ __hip_bfloat16 Bs[128 * 32];
  const int tid = threadIdx.x;
  const int wave = tid >> 6, lane = tid & 63;
  const int l15 = lane & 15, l4 = lane >> 4;
  const int bm = blockIdx.x, bn = blockIdx.y;
  const int wr = (wave >> 1) * 64, wc = (wave & 1) * 64;

  const long arow = (long)(bm * 128 + (tid >> 2)) * K + (tid & 3) * 8;
  const long brow = (long)(bn * 128 + (tid >> 2)) * K + (tid & 3) * 8;

  f32x4 acc[4][4] = {};

  for (int k0 = 0; k0 < K; k0 += 32) {
    const __hip_bfloat16* ga = A + arow + k0;
    const __hip_bfloat16* gb = Bw + brow + k0;
    gl_lds16(ga, As + tid * 8);
    gl_lds16(ga + (long)64 * K, As + 2048 + tid * 8);
    gl_lds16(gb, Bs + tid * 8);
    gl_lds16(gb + (long)64 * K, Bs + 2048 + tid * 8);
    __syncthreads();

    bf16x8 af[4], bg[4];
#pragma unroll
    for (int i = 0; i < 4; i++) {
      af[i] = *(const bf16x8*)(As + (wr + i * 16 + l15) * 32 + l4 * 8);
      bg[i] = *(const bf16x8*)(Bs + (wc + i * 16 + l15) * 32 + l4 * 8);
    }
#pragma unroll
    for (int mi = 0; mi < 4; mi++)
#pragma unroll
      for (int nj = 0; nj < 4; nj++)
        acc[mi][nj] = __builtin_amdgcn_mfma_f32_16x16x32_bf16(af[mi], bg[nj], acc[mi][nj], 0, 0, 0);
    __syncthreads();
  }

  if (MODE == 0) {
    if (bn * 128 < 4096) {
      // Q or K region: fused RoPE (pairs along hd exchanged via shfl_xor 1), -> QK buffer
      const int pos = *posp;
#pragma unroll
      for (int mi = 0; mi < 4; mi++)
#pragma unroll
        for (int nj = 0; nj < 4; nj++) {
          int n = bn * 128 + wc + nj * 16 + l15;
          int hd = n & 127;
          int ip = hd >> 1;
          bool odd = hd & 1;
#pragma unroll
          for (int r = 0; r < 4; r++) {
            float v = acc[mi][nj][r];
            float p = __shfl_xor(v, 1, 64);
            int m = bm * 128 + wr + mi * 16 + l4 * 4 + r;
            int s = m & (SS - 1);
            float cv = fc[(long)(pos + s) * 64 + ip];
            float sv = fs[(long)(pos + s) * 64 + ip];
            float out = odd ? (p * sv + v * cv) : (v * cv - p * sv);
            Cbf[(long)m * 4096 + n] = __float2bfloat16(out);
          }
        }
    } else {
      // V region -> Vt[(b*16+h)*128+hd][s], pack 4 consecutive s
#pragma unroll
      for (int mi = 0; mi < 4; mi++)
#pragma unroll
        for (int nj = 0; nj < 4; nj++) {
          int e = bn * 128 + wc + nj * 16 + l15 - 4096;
          int hh = e >> 7, hd = e & 127;
          int m0 = bm * 128 + wr + mi * 16 + l4 * 4;
          int b = m0 >> 11, s0 = m0 & (SS - 1);
          u16x4 pk;
#pragma unroll
          for (int r = 0; r < 4; r++) pk[r] = f2bf(acc[mi][nj][r]);
          *(u16x4*)(Vt + (((long)(b * HH + hh) * 128 + hd) * SS + s0)) = pk;
        }
    }
  } else {
#pragma unroll
    for (int mi = 0; mi < 4; mi++)
#pragma unroll
      for (int nj = 0; nj < 4; nj++) {
        int n = bn * 128 + wc + nj * 16 + l15;
#pragma unroll
        for (int r = 0; r < 4; r++) {
          int m = bm * 128 + wr + mi * 16 + l4 * 4 + r;
          Cf[(long)m * N + n] = acc[mi][nj][r];
        }
      }
  }
}

// ---------------- causal flash attention ----------------
// 512 blocks (8 q-pairs x 64 bh, XCD-swizzled) x 512 threads (8 waves x 16 q-rows).
// Block does q-tiles qp (KV ascending) then 15-qp (KV DESCENDING). KVBLK=64; LDS
// dbuf; async stage split; defer-max (finite sentinels); exp2 softmax; coalesced
// epilogue. LDS 80KB -> 2 blocks/CU = 16 waves/CU (50% occupancy).
// waves_per_eu(4,4): pin compiler at 128 VGPR / 4 waves-per-EU — LDS caps
// occupancy at 2 blocks/CU anyway; round-6's 64-VGPR choice caused ~400MB of
// scratch spill traffic.
__global__ __launch_bounds__(512)
__attribute__((amdgpu_waves_per_eu(4, 4)))
void attn_k(const __hip_bfloat16* __restrict__ qk,
            const __hip_bfloat16* __restrict__ vt,
            __hip_bfloat16* __restrict__ aout,
            const int* __restrict__ posp) {
  __shared__ __hip_bfloat16 Ks[2][64 * 128];   // [key][hd], XOR-swizzled   (32KB)
  __shared__ __hip_bfloat16 Vs[2][128 * 64];   // [hd][kv] (V^T), swizzled  (32KB)
  __shared__ __hip_bfloat16 Ps[8][16 * 64];    // per-wave P, swizzled      (16KB)
  const int pos = *posp;
  const int orig = blockIdx.x;                  // 512 blocks
  const int swz = (orig & 7) * 64 + (orig >> 3);  // XCD-contiguous
  const int qp = swz & 7, bh = swz >> 3;
  const int b = bh >> 4, h = bh & 15;
  const int tid = threadIdx.x;
  const int wave = tid >> 6, lane = tid & 63;
  const int l15 = lane & 15, l4 = lane >> 4;

  const long kbase = ((long)b * SS) * 4096 + 2048 + h * 128;
  const long vbase = ((long)bh * 128) * SS;
  const float sc2 = 0.08838834764831845f * 1.4426950408889634f;  // 1/sqrt(128)*log2(e)

  // staging decode: 2 chunks/thread (512 threads, 1024 chunks of 8 elems per tile)
  const int s_kr[2] = {(0 * 512 + tid) >> 4, (1 * 512 + tid) >> 4};
  const int s_kc = tid & 15;
  const int s_hd[2] = {(0 * 512 + tid) >> 3, (1 * 512 + tid) >> 3};
  const int s_vc = tid & 7;

  bf16x8 kreg[2], vreg[2];

#define LOADKV(T)                                                                             \
  {                                                                                           \
    const int kv0_ = (T) * 64;                                                                \
    _Pragma("unroll") for (int i = 0; i < 2; i++) {                                           \
      kreg[i] = *(const bf16x8*)(qk + kbase + (long)(kv0_ + s_kr[i]) * 4096 + s_kc * 8);      \
      vreg[i] = *(const bf16x8*)(vt + vbase + (long)s_hd[i] * SS + kv0_ + s_vc * 8);          \
    }                                                                                         \
  }

#define STAGE(BI)                                                                             \
  {                                                                                           \
    _Pragma("unroll") for (int i = 0; i < 2; i++) {                                           \
      *(bf16x8*)(Ks[BI] + ((s_kr[i] * 128 + s_kc * 8) ^ ((s_kr[i] & 7) << 3))) = kreg[i];     \
      *(bf16x8*)(Vs[BI] + ((s_hd[i] * 64 + s_vc * 8) ^ ((s_hd[i] & 7) << 3))) = vreg[i];      \
    }                                                                                         \
  }

  for (int half = 0; half < 2; ++half) {
    const int qb = half ? (15 - qp) : qp;
    const int qwb = qb * 128 + wave * 16;

    // Q fragments in registers (16 q-rows per wave)
    bf16x8 qf[4];
#pragma unroll
    for (int kk = 0; kk < 4; kk++) {
      long row = (long)b * SS + qwb + l15;
      qf[kk] = *(const bf16x8*)(qk + row * 4096 + h * 128 + kk * 32 + l4 * 8);
    }

    f32x4 accO[8] = {};
    float mrun[4], lrun[4];
#pragma unroll
    for (int r = 0; r < 4; r++) { mrun[r] = MINIT; lrun[r] = 0.f; }

    int ntiles = (pos + qb * 128 + 127) / 64 + 1;
    if (ntiles > SS / 64) ntiles = SS / 64;
    // half 0: ascending t; half 1: descending (two shared streams per bh)
#define TT(t) (half ? (ntiles - 1 - (t)) : (t))

    LOADKV(TT(0));
    __syncthreads();   // protect buffers from previous half's last reads
    STAGE(0);

    for (int t = 0; t < ntiles; ++t) {
      const int kv0 = TT(t) * 64;
      const int cur = t & 1;
      if (t + 1 < ntiles) LOADKV(TT(t + 1));   // async: in flight across barrier+compute
      __syncthreads();                          // staged tile visible

      // ---- S = Q K^T ----
      f32x4 sfr[4] = {};
      __builtin_amdgcn_s_setprio(1);
#pragma unroll
      for (int ni = 0; ni < 4; ni++) {
        const int key = ni * 16 + l15;
        const int sw = (key & 7) << 3;
#pragma unroll
        for (int kk = 0; kk < 4; kk++) {
          bf16x8 kf = *(const bf16x8*)(Ks[cur] + ((key * 128 + kk * 32 + l4 * 8) ^ sw));
          sfr[ni] = __builtin_amdgcn_mfma_f32_16x16x32_bf16(qf[kk], kf, sfr[ni], 0, 0, 0);
        }
      }
      __builtin_amdgcn_s_setprio(0);

      // ---- scale (log2 domain) + causal mask (finite sentinel) ----
      const bool needmask = (kv0 + 63) > (pos + qb * 128);
#pragma unroll
      for (int ni = 0; ni < 4; ni++)
#pragma unroll
        for (int r = 0; r < 4; r++) {
          float v = sfr[ni][r] * sc2;
          if (needmask) {
            int key = kv0 + ni * 16 + l15;
            int q = qwb + l4 * 4 + r;
            if (key > pos + q) v = MASKV;
          }
          sfr[ni][r] = v;
        }

      // ---- online softmax with defer-max ----
      {
        f32x4 mx = sfr[0];
#pragma unroll
        for (int ni = 1; ni < 4; ni++)
#pragma unroll
          for (int r = 0; r < 4; r++) mx[r] = fmaxf(mx[r], sfr[ni][r]);
#pragma unroll
        for (int d = 1; d < 16; d <<= 1)
#pragma unroll
          for (int r = 0; r < 4; r++) mx[r] = fmaxf(mx[r], __shfl_xor(mx[r], d, 64));

        float growth = mx[0] - mrun[0];
#pragma unroll
        for (int r = 1; r < 4; r++) growth = fmaxf(growth, mx[r] - mrun[r]);
        if (!__all(growth <= 11.0f)) {
          float scal[4];
#pragma unroll
          for (int r = 0; r < 4; r++) {
            float mn = fmaxf(mrun[r], mx[r]);
            scal[r] = exp2f(mrun[r] - mn);
            mrun[r] = mn;
            lrun[r] *= scal[r];
          }
#pragma unroll
          for (int ni = 0; ni < 8; ni++)
#pragma unroll
            for (int r = 0; r < 4; r++) accO[ni][r] *= scal[r];
        }

        f32x4 rs = {0.f, 0.f, 0.f, 0.f};
#pragma unroll
        for (int ni = 0; ni < 4; ni++)
#pragma unroll
          for (int r = 0; r < 4; r++) {
            float p = exp2f(sfr[ni][r] - mrun[r]);
            rs[r] += p;
            int prow = l4 * 4 + r;
            Ps[wave][(prow * 64 + ni * 16 + l15) ^ ((prow & 7) << 3)] = __float2bfloat16(p);
          }
#pragma unroll
        for (int d = 1; d < 16; d <<= 1)
#pragma unroll
          for (int r = 0; r < 4; r++) rs[r] += __shfl_xor(rs[r], d, 64);
#pragma unroll
        for (int r = 0; r < 4; r++) lrun[r] += rs[r];
      }

      // ---- O += P * V ----
      __builtin_amdgcn_s_setprio(1);
#pragma unroll
      for (int kk = 0; kk < 2; kk++) {
        int prow = l15;
        bf16x8 pf = *(const bf16x8*)(Ps[wave] + ((prow * 64 + kk * 32 + l4 * 8) ^ ((prow & 7) << 3)));
#pragma unroll
        for (int ni = 0; ni < 8; ni++) {
          int hd = ni * 16 + l15;
          bf16x8 vf = *(const bf16x8*)(Vs[cur] + ((hd * 64 + kk * 32 + l4 * 8) ^ ((hd & 7) << 3)));
          accO[ni] = __builtin_amdgcn_mfma_f32_16x16x32_bf16(pf, vf, accO[ni], 0, 0, 0);
        }
      }
      __builtin_amdgcn_s_setprio(0);

      if (t + 1 < ntiles) STAGE(cur ^ 1);
    }
#undef TT

    // ---- epilogue: normalize, LDS-transpose, coalesced 16B stores ----
    __syncthreads();  // all waves done reading Ks/Vs/Ps
    __hip_bfloat16* E = &Ks[0][0] + wave * 2048;  // 16 rows x 128 cols bf16 = 4KB/wave
    {
      float inv[4];
#pragma unroll
      for (int r = 0; r < 4; r++) inv[r] = 1.0f / lrun[r];
#pragma unroll
      for (int ni = 0; ni < 8; ni++)
#pragma unroll
        for (int r = 0; r < 4; r++) {
          int row = l4 * 4 + r;
          E[(row * 128 + ni * 16 + l15) ^ ((row & 7) << 3)] =
              __float2bfloat16(accO[ni][r] * inv[r]);
        }
    }
    const long gb = ((long)b * SS + qwb) * 2048 + h * 128;
    // 16 rows x 128 cols per wave: 4 iters x 64 lanes x 8 elems = 2048
#pragma unroll
    for (int j = 0; j < 4; j++) {
      int row = j * 4 + l4;
      int c8 = l15 * 8;
      bf16x8 v = *(const bf16x8*)(E + ((row * 128 + c8) ^ ((row & 7) << 3)));
      *(bf16x8*)(aout + gb + (long)row * 2048 + c8) = v;
    }
  }
#undef LOADKV
#undef STAGE
}

extern "C" void kernel_launch(void* const* d_in, const int* in_sizes, int n_in,
                              void* d_out, int out_size, void* d_ws, size_t ws_size,
                              hipStream_t stream) {
  (void)in_sizes; (void)n_in; (void)out_size; (void)ws_size;
  const float* h  = (const float*)d_in[0];
  const float* Wq = (const float*)d_in[1];
  const float* Wk = (const float*)d_in[2];
  const float* Wv = (const float*)d_in[3];
  const float* Wo = (const float*)d_in[4];
  const float* fc = (const float*)d_in[7];
  const float* fs = (const float*)d_in[8];
  const int* pos  = (const int*)d_in[9];
  float* out = (float*)d_out;

  char* ws = (char*)d_ws;
  __hip_bfloat16* hb    = (__hip_bfloat16*)(ws);                 // 33,554,432 B
  __hip_bfloat16* wqkv  = (__hip_bfloat16*)(ws + 33554432);      // 25,165,824 B
  __hip_bfloat16* wo_b  = (__hip_bfloat16*)(ws + 58720256);      //  8,388,608 B
  __hip_bfloat16* qkbuf = (__hip_bfloat16*)(ws + 67108864);      // 67,108,864 B
  __hip_bfloat16* vt    = (__hip_bfloat16*)(ws + 134217728);     // 33,554,432 B
  __hip_bfloat16* aout  = hb;  // alias: hb dead after GEMM1

  convertk<<<16384, 256, 0, stream>>>(h, hb, 4194304);
  convertk<<<4096, 256, 0, stream>>>(Wq, wqkv, 1048576);
  convertk<<<4096, 256, 0, stream>>>(Wk, wqkv + 4194304, 1048576);
  convertk<<<4096, 256, 0, stream>>>(Wv, wqkv + 8388608, 1048576);
  convertk<<<4096, 256, 0, stream>>>(Wo, wo_b, 1048576);

  // QKV projection + fused RoPE: M=8192, N=6144, K=2048
  gemm_bt<0><<<dim3(64, 48), 256, 0, stream>>>(hb, wqkv, qkbuf, vt, nullptr, fc, fs, pos,
                                               8192, 6144, 2048);

  // causal flash attention (balanced, two-stream L2-local, 512 blocks x 512 threads)
  attn_k<<<512, 512, 0, stream>>>(qkbuf, vt, aout, pos);

  // output projection: M=8192, N=2048, K=2048 -> fp32 d_out
  gemm_bt<1><<<dim3(64, 16), 256, 0, stream>>>(aout, wo_b, nullptr, nullptr, out, nullptr,
                                               nullptr, nullptr, 8192, 2048, 2048);
}

// Round 8
// 650.564 us; speedup vs baseline: 1.4910x; 1.4910x over previous
//
#include <hip/hip_runtime.h>
#include <hip/hip_bf16.h>

typedef __attribute__((ext_vector_type(8))) short bf16x8;
typedef __attribute__((ext_vector_type(4))) float f32x4;
typedef __attribute__((ext_vector_type(4))) unsigned short u16x4;

#define BB 4
#define SS 2048
#define DD 2048
#define HH 16
#define HDD 128
// QK buffer: [B*S][4096] bf16 (Q cols 0..2047, K cols 2048..4095), RoPE pre-applied
// Vt buffer: [B*H][128][2048] bf16 (V transposed: hd-major, s contiguous)
// Masking sentinels: finite so (masked) - (init) never yields exp2(0)=1.
#define MASKV (-30000.0f)
#define MINIT (-15000.0f)

__device__ __forceinline__ unsigned short f2bf(float f) {
  __hip_bfloat16 b = __float2bfloat16(f);
  return *reinterpret_cast<unsigned short*>(&b);
}
__device__ __forceinline__ void gl_lds16(const void* g, void* l) {
  __builtin_amdgcn_global_load_lds((const __attribute__((address_space(1))) unsigned int*)g,
                                   (__attribute__((address_space(3))) unsigned int*)l, 16, 0, 0);
}

// ---------------- fp32 -> bf16 conversion (vectorized) ----------------
__global__ __launch_bounds__(256) void convertk(const float* __restrict__ src,
                                                __hip_bfloat16* __restrict__ dst, int n4) {
  int i = blockIdx.x * 256 + threadIdx.x;
  if (i >= n4) return;
  f32x4 v = ((const f32x4*)src)[i];
  u16x4 o;
  o[0] = f2bf(v[0]); o[1] = f2bf(v[1]); o[2] = f2bf(v[2]); o[3] = f2bf(v[3]);
  ((u16x4*)dst)[i] = o;
}

// ---------------- B^T GEMM: C[m][n] = sum_k A[m][k] * Bw[n][k] ----------------
// MODE 0: epilogue -> QK buffer with fused RoPE (n<4096) or Vt (n>=4096, transposed)
// MODE 1: epilogue -> float C row-major [M][N]
template <int MODE>
__global__ __launch_bounds__(256) void gemm_bt(const __hip_bfloat16* __restrict__ A,
                                               const __hip_bfloat16* __restrict__ Bw,
                                               __hip_bfloat16* __restrict__ Cbf,
                                               __hip_bfloat16* __restrict__ Vt,
                                               float* __restrict__ Cf,
                                               const float* __restrict__ fc,
                                               const float* __restrict__ fs,
                                               const int* __restrict__ posp,
                                               int M, int N, int K) {
  __shared__ __hip_bfloat16 As[128 * 32];
  __shared__ __hip_bfloat16 Bs[128 * 32];
  const int tid = threadIdx.x;
  const int wave = tid >> 6, lane = tid & 63;
  const int l15 = lane & 15, l4 = lane >> 4;
  const int bm = blockIdx.x, bn = blockIdx.y;
  const int wr = (wave >> 1) * 64, wc = (wave & 1) * 64;

  const long arow = (long)(bm * 128 + (tid >> 2)) * K + (tid & 3) * 8;
  const long brow = (long)(bn * 128 + (tid >> 2)) * K + (tid & 3) * 8;

  f32x4 acc[4][4] = {};

  for (int k0 = 0; k0 < K; k0 += 32) {
    const __hip_bfloat16* ga = A + arow + k0;
    const __hip_bfloat16* gb = Bw + brow + k0;
    gl_lds16(ga, As + tid * 8);
    gl_lds16(ga + (long)64 * K, As + 2048 + tid * 8);
    gl_lds16(gb, Bs + tid * 8);
    gl_lds16(gb + (long)64 * K, Bs + 2048 + tid * 8);
    __syncthreads();

    bf16x8 af[4], bg[4];
#pragma unroll
    for (int i = 0; i < 4; i++) {
      af[i] = *(const bf16x8*)(As + (wr + i * 16 + l15) * 32 + l4 * 8);
      bg[i] = *(const bf16x8*)(Bs + (wc + i * 16 + l15) * 32 + l4 * 8);
    }
#pragma unroll
    for (int mi = 0; mi < 4; mi++)
#pragma unroll
      for (int nj = 0; nj < 4; nj++)
        acc[mi][nj] = __builtin_amdgcn_mfma_f32_16x16x32_bf16(af[mi], bg[nj], acc[mi][nj], 0, 0, 0);
    __syncthreads();
  }

  if (MODE == 0) {
    if (bn * 128 < 4096) {
      // Q or K region: fused RoPE (pairs along hd exchanged via shfl_xor 1), -> QK buffer
      const int pos = *posp;
#pragma unroll
      for (int mi = 0; mi < 4; mi++)
#pragma unroll
        for (int nj = 0; nj < 4; nj++) {
          int n = bn * 128 + wc + nj * 16 + l15;
          int hd = n & 127;
          int ip = hd >> 1;
          bool odd = hd & 1;
#pragma unroll
          for (int r = 0; r < 4; r++) {
            float v = acc[mi][nj][r];
            float p = __shfl_xor(v, 1, 64);
            int m = bm * 128 + wr + mi * 16 + l4 * 4 + r;
            int s = m & (SS - 1);
            float cv = fc[(long)(pos + s) * 64 + ip];
            float sv = fs[(long)(pos + s) * 64 + ip];
            float out = odd ? (p * sv + v * cv) : (v * cv - p * sv);
            Cbf[(long)m * 4096 + n] = __float2bfloat16(out);
          }
        }
    } else {
      // V region -> Vt[(b*16+h)*128+hd][s], pack 4 consecutive s
#pragma unroll
      for (int mi = 0; mi < 4; mi++)
#pragma unroll
        for (int nj = 0; nj < 4; nj++) {
          int e = bn * 128 + wc + nj * 16 + l15 - 4096;
          int hh = e >> 7, hd = e & 127;
          int m0 = bm * 128 + wr + mi * 16 + l4 * 4;
          int b = m0 >> 11, s0 = m0 & (SS - 1);
          u16x4 pk;
#pragma unroll
          for (int r = 0; r < 4; r++) pk[r] = f2bf(acc[mi][nj][r]);
          *(u16x4*)(Vt + (((long)(b * HH + hh) * 128 + hd) * SS + s0)) = pk;
        }
    }
  } else {
#pragma unroll
    for (int mi = 0; mi < 4; mi++)
#pragma unroll
      for (int nj = 0; nj < 4; nj++) {
        int n = bn * 128 + wc + nj * 16 + l15;
#pragma unroll
        for (int r = 0; r < 4; r++) {
          int m = bm * 128 + wr + mi * 16 + l4 * 4 + r;
          Cf[(long)m * N + n] = acc[mi][nj][r];
        }
      }
  }
}

// ---------------- causal flash attention ----------------
// 1024 blocks (16 q-pairs x 64 bh, XCD-swizzled) x 256 threads (4 waves x 16 q-rows,
// 64 q-rows/block). Block does q-tile qp (KV ascending) then 31-qp (KV descending):
// 33 KV tiles each, perfectly balanced; 4 blocks/CU exactly. KVBLK=64; SINGLE-buffered
// K/V LDS (40KB total -> 4 blocks/CU = 16 waves/CU) with register prefetch of tile
// t+1 issued before compute(t); defer-max (finite sentinels); exp2 softmax;
// coalesced epilogue. 256-thr + launch_bounds(256,2): compiler allocates ~128 VGPR
// (rounds 1-5 evidence) — avoids the 64-VGPR spill the 512-thr shape triggered.
__global__ __launch_bounds__(256, 2) void attn_k(const __hip_bfloat16* __restrict__ qk,
                                                 const __hip_bfloat16* __restrict__ vt,
                                                 __hip_bfloat16* __restrict__ aout,
                                                 const int* __restrict__ posp) {
  __shared__ __hip_bfloat16 Ks[64 * 128];   // [key][hd], XOR-swizzled   (16KB)
  __shared__ __hip_bfloat16 Vs[128 * 64];   // [hd][kv] (V^T), swizzled  (16KB)
  __shared__ __hip_bfloat16 Ps[4][16 * 64]; // per-wave P, swizzled      ( 8KB)
  const int pos = *posp;
  const int orig = blockIdx.x;                   // 1024 blocks
  const int swz = (orig & 7) * 128 + (orig >> 3);  // XCD-contiguous
  const int qp = swz & 15, bh = swz >> 4;
  const int b = bh >> 4, h = bh & 15;
  const int tid = threadIdx.x;
  const int wave = tid >> 6, lane = tid & 63;
  const int l15 = lane & 15, l4 = lane >> 4;

  const long kbase = ((long)b * SS) * 4096 + 2048 + h * 128;
  const long vbase = ((long)bh * 128) * SS;
  const float sc2 = 0.08838834764831845f * 1.4426950408889634f;  // 1/sqrt(128)*log2(e)

  // staging decode: 4 chunks/thread (256 threads, 1024 chunks of 8 elems per tile)
  const int s_kr[4] = {(0 * 256 + tid) >> 4, (1 * 256 + tid) >> 4, (2 * 256 + tid) >> 4, (3 * 256 + tid) >> 4};
  const int s_kc = tid & 15;
  const int s_hd[4] = {(0 * 256 + tid) >> 3, (1 * 256 + tid) >> 3, (2 * 256 + tid) >> 3, (3 * 256 + tid) >> 3};
  const int s_vc = tid & 7;

  bf16x8 kreg[4], vreg[4];

#define LOADKV(T)                                                                             \
  {                                                                                           \
    const int kv0_ = (T) * 64;                                                                \
    _Pragma("unroll") for (int i = 0; i < 4; i++) {                                           \
      kreg[i] = *(const bf16x8*)(qk + kbase + (long)(kv0_ + s_kr[i]) * 4096 + s_kc * 8);      \
      vreg[i] = *(const bf16x8*)(vt + vbase + (long)s_hd[i] * SS + kv0_ + s_vc * 8);          \
    }                                                                                         \
  }

#define STAGE()                                                                               \
  {                                                                                           \
    _Pragma("unroll") for (int i = 0; i < 4; i++) {                                           \
      *(bf16x8*)(Ks + ((s_kr[i] * 128 + s_kc * 8) ^ ((s_kr[i] & 7) << 3))) = kreg[i];         \
      *(bf16x8*)(Vs + ((s_hd[i] * 64 + s_vc * 8) ^ ((s_hd[i] & 7) << 3))) = vreg[i];          \
    }                                                                                         \
  }

  for (int half = 0; half < 2; ++half) {
    const int qb = half ? (31 - qp) : qp;     // q-tiles of 64 rows (0..31)
    const int qwb = qb * 64 + wave * 16;

    // Q fragments in registers (16 q-rows per wave)
    bf16x8 qf[4];
#pragma unroll
    for (int kk = 0; kk < 4; kk++) {
      long row = (long)b * SS + qwb + l15;
      qf[kk] = *(const bf16x8*)(qk + row * 4096 + h * 128 + kk * 32 + l4 * 8);
    }

    f32x4 accO[8] = {};
    float mrun[4], lrun[4];
#pragma unroll
    for (int r = 0; r < 4; r++) { mrun[r] = MINIT; lrun[r] = 0.f; }

    int ntiles = (pos + qb * 64 + 63) / 64 + 1;
    if (ntiles > SS / 64) ntiles = SS / 64;
    // half 0: ascending t; half 1: descending (two shared streams per bh)
#define TT(t) (half ? (ntiles - 1 - (t)) : (t))

    LOADKV(TT(0));
    __syncthreads();   // previous half's epilogue reads of Ks done
    STAGE();

    for (int t = 0; t < ntiles; ++t) {
      const int kv0 = TT(t) * 64;
      __syncthreads();                         // staged tile t visible
      if (t + 1 < ntiles) LOADKV(TT(t + 1));   // prefetch into regs, hides under compute

      // ---- S = Q K^T ----
      f32x4 sfr[4] = {};
      __builtin_amdgcn_s_setprio(1);
#pragma unroll
      for (int ni = 0; ni < 4; ni++) {
        const int key = ni * 16 + l15;
        const int sw = (key & 7) << 3;
#pragma unroll
        for (int kk = 0; kk < 4; kk++) {
          bf16x8 kf = *(const bf16x8*)(Ks + ((key * 128 + kk * 32 + l4 * 8) ^ sw));
          sfr[ni] = __builtin_amdgcn_mfma_f32_16x16x32_bf16(qf[kk], kf, sfr[ni], 0, 0, 0);
        }
      }
      __builtin_amdgcn_s_setprio(0);

      // ---- scale (log2 domain) + causal mask (finite sentinel) ----
      const bool needmask = (kv0 + 63) > (pos + qb * 64);
#pragma unroll
      for (int ni = 0; ni < 4; ni++)
#pragma unroll
        for (int r = 0; r < 4; r++) {
          float v = sfr[ni][r] * sc2;
          if (needmask) {
            int key = kv0 + ni * 16 + l15;
            int q = qwb + l4 * 4 + r;
            if (key > pos + q) v = MASKV;
          }
          sfr[ni][r] = v;
        }

      // ---- online softmax with defer-max ----
      {
        f32x4 mx = sfr[0];
#pragma unroll
        for (int ni = 1; ni < 4; ni++)
#pragma unroll
          for (int r = 0; r < 4; r++) mx[r] = fmaxf(mx[r], sfr[ni][r]);
#pragma unroll
        for (int d = 1; d < 16; d <<= 1)
#pragma unroll
          for (int r = 0; r < 4; r++) mx[r] = fmaxf(mx[r], __shfl_xor(mx[r], d, 64));

        float growth = mx[0] - mrun[0];
#pragma unroll
        for (int r = 1; r < 4; r++) growth = fmaxf(growth, mx[r] - mrun[r]);
        if (!__all(growth <= 11.0f)) {
          float scal[4];
#pragma unroll
          for (int r = 0; r < 4; r++) {
            float mn = fmaxf(mrun[r], mx[r]);
            scal[r] = exp2f(mrun[r] - mn);
            mrun[r] = mn;
            lrun[r] *= scal[r];
          }
#pragma unroll
          for (int ni = 0; ni < 8; ni++)
#pragma unroll
            for (int r = 0; r < 4; r++) accO[ni][r] *= scal[r];
        }

        f32x4 rs = {0.f, 0.f, 0.f, 0.f};
#pragma unroll
        for (int ni = 0; ni < 4; ni++)
#pragma unroll
          for (int r = 0; r < 4; r++) {
            float p = exp2f(sfr[ni][r] - mrun[r]);
            rs[r] += p;
            int prow = l4 * 4 + r;
            Ps[wave][(prow * 64 + ni * 16 + l15) ^ ((prow & 7) << 3)] = __float2bfloat16(p);
          }
#pragma unroll
        for (int d = 1; d < 16; d <<= 1)
#pragma unroll
          for (int r = 0; r < 4; r++) rs[r] += __shfl_xor(rs[r], d, 64);
#pragma unroll
        for (int r = 0; r < 4; r++) lrun[r] += rs[r];
      }

      // ---- O += P * V ----
      __builtin_amdgcn_s_setprio(1);
#pragma unroll
      for (int kk = 0; kk < 2; kk++) {
        int prow = l15;
        bf16x8 pf = *(const bf16x8*)(Ps[wave] + ((prow * 64 + kk * 32 + l4 * 8) ^ ((prow & 7) << 3)));
#pragma unroll
        for (int ni = 0; ni < 8; ni++) {
          int hd = ni * 16 + l15;
          bf16x8 vf = *(const bf16x8*)(Vs + ((hd * 64 + kk * 32 + l4 * 8) ^ ((hd & 7) << 3)));
          accO[ni] = __builtin_amdgcn_mfma_f32_16x16x32_bf16(pf, vf, accO[ni], 0, 0, 0);
        }
      }
      __builtin_amdgcn_s_setprio(0);

      __syncthreads();                         // tile t fully consumed
      if (t + 1 < ntiles) STAGE();             // overwrite LDS with tile t+1
    }
#undef TT

    // ---- epilogue: normalize, LDS-transpose, coalesced 16B stores ----
    // (final loop barrier already synced all waves; E regions are per-wave)
    __hip_bfloat16* E = Ks + wave * 2048;  // 16 rows x 128 cols bf16 = 4KB/wave
    {
      float inv[4];
#pragma unroll
      for (int r = 0; r < 4; r++) inv[r] = 1.0f / lrun[r];
#pragma unroll
      for (int ni = 0; ni < 8; ni++)
#pragma unroll
        for (int r = 0; r < 4; r++) {
          int row = l4 * 4 + r;
          E[(row * 128 + ni * 16 + l15) ^ ((row & 7) << 3)] =
              __float2bfloat16(accO[ni][r] * inv[r]);
        }
    }
    const long gb = ((long)b * SS + qwb) * 2048 + h * 128;
    // 16 rows x 128 cols per wave: 4 iters x 64 lanes x 8 elems = 2048
#pragma unroll
    for (int j = 0; j < 4; j++) {
      int row = j * 4 + l4;
      int c8 = l15 * 8;
      bf16x8 v = *(const bf16x8*)(E + ((row * 128 + c8) ^ ((row & 7) << 3)));
      *(bf16x8*)(aout + gb + (long)row * 2048 + c8) = v;
    }
  }
#undef LOADKV
#undef STAGE
}

extern "C" void kernel_launch(void* const* d_in, const int* in_sizes, int n_in,
                              void* d_out, int out_size, void* d_ws, size_t ws_size,
                              hipStream_t stream) {
  (void)in_sizes; (void)n_in; (void)out_size; (void)ws_size;
  const float* h  = (const float*)d_in[0];
  const float* Wq = (const float*)d_in[1];
  const float* Wk = (const float*)d_in[2];
  const float* Wv = (const float*)d_in[3];
  const float* Wo = (const float*)d_in[4];
  const float* fc = (const float*)d_in[7];
  const float* fs = (const float*)d_in[8];
  const int* pos  = (const int*)d_in[9];
  float* out = (float*)d_out;

  char* ws = (char*)d_ws;
  __hip_bfloat16* hb    = (__hip_bfloat16*)(ws);                 // 33,554,432 B
  __hip_bfloat16* wqkv  = (__hip_bfloat16*)(ws + 33554432);      // 25,165,824 B
  __hip_bfloat16* wo_b  = (__hip_bfloat16*)(ws + 58720256);      //  8,388,608 B
  __hip_bfloat16* qkbuf = (__hip_bfloat16*)(ws + 67108864);      // 67,108,864 B
  __hip_bfloat16* vt    = (__hip_bfloat16*)(ws + 134217728);     // 33,554,432 B
  __hip_bfloat16* aout  = hb;  // alias: hb dead after GEMM1

  convertk<<<16384, 256, 0, stream>>>(h, hb, 4194304);
  convertk<<<4096, 256, 0, stream>>>(Wq, wqkv, 1048576);
  convertk<<<4096, 256, 0, stream>>>(Wk, wqkv + 4194304, 1048576);
  convertk<<<4096, 256, 0, stream>>>(Wv, wqkv + 8388608, 1048576);
  convertk<<<4096, 256, 0, stream>>>(Wo, wo_b, 1048576);

  // QKV projection + fused RoPE: M=8192, N=6144, K=2048
  gemm_bt<0><<<dim3(64, 48), 256, 0, stream>>>(hb, wqkv, qkbuf, vt, nullptr, fc, fs, pos,
                                               8192, 6144, 2048);

  // causal flash attention (balanced, two-stream L2-local, 1024 blocks x 256 threads)
  attn_k<<<1024, 256, 0, stream>>>(qkbuf, vt, aout, pos);

  // output projection: M=8192, N=2048, K=2048 -> fp32 d_out
  gemm_bt<1><<<dim3(64, 16), 256, 0, stream>>>(aout, wo_b, nullptr, nullptr, out, nullptr,
                                               nullptr, nullptr, 8192, 2048, 2048);
}

// Round 9
// 532.880 us; speedup vs baseline: 1.8203x; 1.2208x over previous
//
#include <hip/hip_runtime.h>
#include <hip/hip_bf16.h>

typedef __attribute__((ext_vector_type(8))) short bf16x8;
typedef __attribute__((ext_vector_type(4))) float f32x4;
typedef __attribute__((ext_vector_type(4))) unsigned short u16x4;

#define BB 4
#define SS 2048
#define DD 2048
#define HH 16
#define HDD 128
// QK buffer: [B*S][4096] bf16 (Q cols 0..2047, K cols 2048..4095), RoPE pre-applied
// Vt buffer: [B*H][128][2048] bf16 (V transposed: hd-major, s contiguous)
// Masking sentinels: finite so (masked) - (init) never yields exp2(0)=1.
#define MASKV (-30000.0f)
#define MINIT (-15000.0f)

__device__ __forceinline__ unsigned short f2bf(float f) {
  __hip_bfloat16 b = __float2bfloat16(f);
  return *reinterpret_cast<unsigned short*>(&b);
}
__device__ __forceinline__ void gl_lds16(const void* g, void* l) {
  __builtin_amdgcn_global_load_lds((const __attribute__((address_space(1))) unsigned int*)g,
                                   (__attribute__((address_space(3))) unsigned int*)l, 16, 0, 0);
}

// ---------------- fp32 -> bf16 conversion (vectorized) ----------------
__global__ __launch_bounds__(256) void convertk(const float* __restrict__ src,
                                                __hip_bfloat16* __restrict__ dst, int n4) {
  int i = blockIdx.x * 256 + threadIdx.x;
  if (i >= n4) return;
  f32x4 v = ((const f32x4*)src)[i];
  u16x4 o;
  o[0] = f2bf(v[0]); o[1] = f2bf(v[1]); o[2] = f2bf(v[2]); o[3] = f2bf(v[3]);
  ((u16x4*)dst)[i] = o;
}

// ---------------- 256x256 8-wave 4-phase B^T GEMM ----------------
// C[m][n] = sum_k A[m][k] * Bw[n][k].  BK=64, double-buffered 128KB LDS,
// XOR-swizzle (chunk ^= row&7) staged via inverse-swizzled global source
// (global_load_lds writes linearly). Per K-tile: 4 phases, each
// {12 ds_read frags | stage 1 half of tile T+1 | barrier | 16 MFMA | barrier},
// one vmcnt(0) per tile at phase 3 (loads issued 1-4 phases earlier).
// MODE 0: epilogue -> QK buffer with fused RoPE (n<4096) or Vt (transposed).
// MODE 1: epilogue -> float C row-major [M][N].
template <int MODE>
__global__ __launch_bounds__(512, 1) void gemm256(const __hip_bfloat16* __restrict__ A,
                                                  const __hip_bfloat16* __restrict__ Bw,
                                                  __hip_bfloat16* __restrict__ Cbf,
                                                  __hip_bfloat16* __restrict__ Vt,
                                                  float* __restrict__ Cf,
                                                  const float* __restrict__ fc,
                                                  const float* __restrict__ fs,
                                                  const int* __restrict__ posp,
                                                  int M, int N, int K) {
  __shared__ __hip_bfloat16 As[2][2][128 * 64];  // [buf][half][row*64+col]  64KB
  __shared__ __hip_bfloat16 Bs[2][2][128 * 64];  // 64KB
  const int tid = threadIdx.x;
  const int wid = tid >> 6, lane = tid & 63;
  const int l15 = lane & 15, l4 = lane >> 4;
  const int wm = wid >> 2, wn = wid & 3;  // 2 x 4 wave grid; wave owns 128x64

  const int nbn = N >> 8;
  const int nb = (M >> 8) * nbn;
  const int bid = blockIdx.x;
  const int swz = (bid & 7) * (nb >> 3) + (bid >> 3);  // XCD-contiguous (nb%8==0)
  const int bm = swz / nbn, bn = swz % nbn;

  const int NT = K >> 6;  // K-tiles of 64

// stage half Q (0,1=A half; 2,3=B half) of K-offset K0G into buffer BUF.
// 512 threads x 2 loads cover 1024 chunks of 16B; source col pre-swizzled.
#define STAGE_HALF(Q, BUF, K0G)                                                   \
  {                                                                               \
    if ((Q) < 2) {                                                                \
      const long rowb = (long)bm * 256 + (Q) * 128;                               \
      _Pragma("unroll") for (int i = 0; i < 2; i++) {                             \
        int c = i * 512 + tid, rr = c >> 3, jj = (c & 7) ^ (rr & 7);              \
        gl_lds16(A + (rowb + rr) * (long)K + (K0G) + jj * 8,                      \
                 &As[BUF][(Q)][0] + c * 8);                                       \
      }                                                                           \
    } else {                                                                      \
      const long rowb = (long)bn * 256 + ((Q) - 2) * 128;                         \
      _Pragma("unroll") for (int i = 0; i < 2; i++) {                             \
        int c = i * 512 + tid, rr = c >> 3, jj = (c & 7) ^ (rr & 7);              \
        gl_lds16(Bw + (rowb + rr) * (long)K + (K0G) + jj * 8,                     \
                 &Bs[BUF][(Q) - 2][0] + c * 8);                                   \
      }                                                                           \
    }                                                                             \
  }

  f32x4 acc[8][4] = {};

  // prologue: tiles 0 and 1 fully staged
#pragma unroll
  for (int q = 0; q < 4; ++q) STAGE_HALF(q, 0, 0);
#pragma unroll
  for (int q = 0; q < 4; ++q) STAGE_HALF(q, 1, 64);
  __syncthreads();  // vmcnt(0)+lgkm(0)+barrier

  for (int T = 0; T < NT; ++T) {
    const int cur = T & 1;
    const int nxt = cur ^ 1;
    const bool pf = (T + 2 < NT);       // stage tile T+2 into buf nxt... no:
    // buf[nxt] holds tile T+1 (unconsumed). We stage tile T+2 only AFTER buf[nxt]
    // is consumed -> stage target must be buf[cur], tile T+2, during NEXT tile's
    // phases. Equivalent formulation: during tile T's phases stage tile T+2's
    // halves into buf[cur]?? buf[cur] is being read now. Correct scheme: stage
    // tile T+2 during tile T+1's phases. Implemented as: during tile T, stage
    // tile T+1's... tile T+1 already staged. => stage tile T+2 into buf[cur]
    // is illegal during T. So: stage during tile T the halves of tile T+2 is
    // impossible with 2 buffers; instead stage tile T+1's REPLACEMENT (tile T+2)
    // in the tile that consumes buf[cur^1]. Net: during tile T we stage nothing
    // for the first tile pair; from T>=1 we stage tile T+1 into the buffer just
    // freed (the one tile T-1 used = buf[nxt]).   [resolved below]
    (void)pf;
    const bool do_stage = (T >= 1) && (T + 1 < NT);
    const int k0n = (T + 1) << 6;

#pragma unroll
    for (int q = 0; q < 4; ++q) {
      const int mq = q >> 1, nq = q & 1;
      bf16x8 af[4][2], bg[2][2];
#pragma unroll
      for (int i = 0; i < 4; i++)
#pragma unroll
        for (int k2 = 0; k2 < 2; k2++) {
          int r = (mq * 4 + i) * 16 + l15;
          int j = (k2 * 4 + l4) ^ (r & 7);
          af[i][k2] = *(const bf16x8*)(&As[cur][wm][0] + r * 64 + j * 8);
        }
#pragma unroll
      for (int i = 0; i < 2; i++)
#pragma unroll
        for (int k2 = 0; k2 < 2; k2++) {
          int r = (wn & 1) * 64 + (nq * 2 + i) * 16 + l15;
          int j = (k2 * 4 + l4) ^ (r & 7);
          bg[i][k2] = *(const bf16x8*)(&Bs[cur][wn >> 1][0] + r * 64 + j * 8);
        }
      if (do_stage) STAGE_HALF(q, nxt, k0n);  // tile T+1 into buffer freed by T-1
      __builtin_amdgcn_s_barrier();
      asm volatile("" ::: "memory");
      __builtin_amdgcn_s_setprio(1);
#pragma unroll
      for (int i = 0; i < 4; i++)
#pragma unroll
        for (int i2 = 0; i2 < 2; i2++)
#pragma unroll
          for (int k2 = 0; k2 < 2; k2++)
            acc[mq * 4 + i][nq * 2 + i2] = __builtin_amdgcn_mfma_f32_16x16x32_bf16(
                af[i][k2], bg[i2][k2], acc[mq * 4 + i][nq * 2 + i2], 0, 0, 0);
      __builtin_amdgcn_s_setprio(0);
      if (q == 3) asm volatile("s_waitcnt vmcnt(0)" ::: "memory");
      __builtin_amdgcn_s_barrier();
      asm volatile("" ::: "memory");
    }
  }
#undef STAGE_HALF

  // ---- epilogue ----
  if (MODE == 0) {
    if (bn * 256 < 4096) {
      const int pos = *posp;
#pragma unroll
      for (int mi = 0; mi < 8; mi++)
#pragma unroll
        for (int ni = 0; ni < 4; ni++) {
          int n = bn * 256 + wn * 64 + ni * 16 + l15;
          int hd = n & 127;
          int ip = hd >> 1;
          bool odd = hd & 1;
#pragma unroll
          for (int r = 0; r < 4; r++) {
            float v = acc[mi][ni][r];
            float p = __shfl_xor(v, 1, 64);
            int m = bm * 256 + wm * 128 + mi * 16 + l4 * 4 + r;
            int s = m & (SS - 1);
            float cv = fc[(long)(pos + s) * 64 + ip];
            float sv = fs[(long)(pos + s) * 64 + ip];
            float out = odd ? (p * sv + v * cv) : (v * cv - p * sv);
            Cbf[(long)m * 4096 + n] = __float2bfloat16(out);
          }
        }
    } else {
#pragma unroll
      for (int mi = 0; mi < 8; mi++)
#pragma unroll
        for (int ni = 0; ni < 4; ni++) {
          int e = bn * 256 + wn * 64 + ni * 16 + l15 - 4096;
          int hh = e >> 7, hd = e & 127;
          int m0 = bm * 256 + wm * 128 + mi * 16 + l4 * 4;
          int b = m0 >> 11, s0 = m0 & (SS - 1);
          u16x4 pk;
#pragma unroll
          for (int r = 0; r < 4; r++) pk[r] = f2bf(acc[mi][ni][r]);
          *(u16x4*)(Vt + (((long)(b * HH + hh) * 128 + hd) * SS + s0)) = pk;
        }
    }
  } else {
#pragma unroll
    for (int mi = 0; mi < 8; mi++)
#pragma unroll
      for (int ni = 0; ni < 4; ni++) {
        int n = bn * 256 + wn * 64 + ni * 16 + l15;
#pragma unroll
        for (int r = 0; r < 4; r++) {
          int m = bm * 256 + wm * 128 + mi * 16 + l4 * 4 + r;
          Cf[(long)m * N + n] = acc[mi][ni][r];
        }
      }
  }
}

// ---------------- causal flash attention (round-8, unchanged) ----------------
__global__ __launch_bounds__(256, 2) void attn_k(const __hip_bfloat16* __restrict__ qk,
                                                 const __hip_bfloat16* __restrict__ vt,
                                                 __hip_bfloat16* __restrict__ aout,
                                                 const int* __restrict__ posp) {
  __shared__ __hip_bfloat16 Ks[64 * 128];
  __shared__ __hip_bfloat16 Vs[128 * 64];
  __shared__ __hip_bfloat16 Ps[4][16 * 64];
  const int pos = *posp;
  const int orig = blockIdx.x;
  const int swz = (orig & 7) * 128 + (orig >> 3);
  const int qp = swz & 15, bh = swz >> 4;
  const int b = bh >> 4, h = bh & 15;
  const int tid = threadIdx.x;
  const int wave = tid >> 6, lane = tid & 63;
  const int l15 = lane & 15, l4 = lane >> 4;

  const long kbase = ((long)b * SS) * 4096 + 2048 + h * 128;
  const long vbase = ((long)bh * 128) * SS;
  const float sc2 = 0.08838834764831845f * 1.4426950408889634f;

  const int s_kr[4] = {(0 * 256 + tid) >> 4, (1 * 256 + tid) >> 4, (2 * 256 + tid) >> 4, (3 * 256 + tid) >> 4};
  const int s_kc = tid & 15;
  const int s_hd[4] = {(0 * 256 + tid) >> 3, (1 * 256 + tid) >> 3, (2 * 256 + tid) >> 3, (3 * 256 + tid) >> 3};
  const int s_vc = tid & 7;

  bf16x8 kreg[4], vreg[4];

#define LOADKV(T)                                                                             \
  {                                                                                           \
    const int kv0_ = (T) * 64;                                                                \
    _Pragma("unroll") for (int i = 0; i < 4; i++) {                                           \
      kreg[i] = *(const bf16x8*)(qk + kbase + (long)(kv0_ + s_kr[i]) * 4096 + s_kc * 8);      \
      vreg[i] = *(const bf16x8*)(vt + vbase + (long)s_hd[i] * SS + kv0_ + s_vc * 8);          \
    }                                                                                         \
  }

#define STAGE()                                                                               \
  {                                                                                           \
    _Pragma("unroll") for (int i = 0; i < 4; i++) {                                           \
      *(bf16x8*)(Ks + ((s_kr[i] * 128 + s_kc * 8) ^ ((s_kr[i] & 7) << 3))) = kreg[i];         \
      *(bf16x8*)(Vs + ((s_hd[i] * 64 + s_vc * 8) ^ ((s_hd[i] & 7) << 3))) = vreg[i];          \
    }                                                                                         \
  }

  for (int half = 0; half < 2; ++half) {
    const int qb = half ? (31 - qp) : qp;
    const int qwb = qb * 64 + wave * 16;

    bf16x8 qf[4];
#pragma unroll
    for (int kk = 0; kk < 4; kk++) {
      long row = (long)b * SS + qwb + l15;
      qf[kk] = *(const bf16x8*)(qk + row * 4096 + h * 128 + kk * 32 + l4 * 8);
    }

    f32x4 accO[8] = {};
    float mrun[4], lrun[4];
#pragma unroll
    for (int r = 0; r < 4; r++) { mrun[r] = MINIT; lrun[r] = 0.f; }

    int ntiles = (pos + qb * 64 + 63) / 64 + 1;
    if (ntiles > SS / 64) ntiles = SS / 64;
#define TT(t) (half ? (ntiles - 1 - (t)) : (t))

    LOADKV(TT(0));
    __syncthreads();
    STAGE();

    for (int t = 0; t < ntiles; ++t) {
      const int kv0 = TT(t) * 64;
      __syncthreads();
      if (t + 1 < ntiles) LOADKV(TT(t + 1));

      f32x4 sfr[4] = {};
      __builtin_amdgcn_s_setprio(1);
#pragma unroll
      for (int ni = 0; ni < 4; ni++) {
        const int key = ni * 16 + l15;
        const int sw = (key & 7) << 3;
#pragma unroll
        for (int kk = 0; kk < 4; kk++) {
          bf16x8 kf = *(const bf16x8*)(Ks + ((key * 128 + kk * 32 + l4 * 8) ^ sw));
          sfr[ni] = __builtin_amdgcn_mfma_f32_16x16x32_bf16(qf[kk], kf, sfr[ni], 0, 0, 0);
        }
      }
      __builtin_amdgcn_s_setprio(0);

      const bool needmask = (kv0 + 63) > (pos + qb * 64);
#pragma unroll
      for (int ni = 0; ni < 4; ni++)
#pragma unroll
        for (int r = 0; r < 4; r++) {
          float v = sfr[ni][r] * sc2;
          if (needmask) {
            int key = kv0 + ni * 16 + l15;
            int q = qwb + l4 * 4 + r;
            if (key > pos + q) v = MASKV;
          }
          sfr[ni][r] = v;
        }

      {
        f32x4 mx = sfr[0];
#pragma unroll
        for (int ni = 1; ni < 4; ni++)
#pragma unroll
          for (int r = 0; r < 4; r++) mx[r] = fmaxf(mx[r], sfr[ni][r]);
#pragma unroll
        for (int d = 1; d < 16; d <<= 1)
#pragma unroll
          for (int r = 0; r < 4; r++) mx[r] = fmaxf(mx[r], __shfl_xor(mx[r], d, 64));

        float growth = mx[0] - mrun[0];
#pragma unroll
        for (int r = 1; r < 4; r++) growth = fmaxf(growth, mx[r] - mrun[r]);
        if (!__all(growth <= 11.0f)) {
          float scal[4];
#pragma unroll
          for (int r = 0; r < 4; r++) {
            float mn = fmaxf(mrun[r], mx[r]);
            scal[r] = exp2f(mrun[r] - mn);
            mrun[r] = mn;
            lrun[r] *= scal[r];
          }
#pragma unroll
          for (int ni = 0; ni < 8; ni++)
#pragma unroll
            for (int r = 0; r < 4; r++) accO[ni][r] *= scal[r];
        }

        f32x4 rs = {0.f, 0.f, 0.f, 0.f};
#pragma unroll
        for (int ni = 0; ni < 4; ni++)
#pragma unroll
          for (int r = 0; r < 4; r++) {
            float p = exp2f(sfr[ni][r] - mrun[r]);
            rs[r] += p;
            int prow = l4 * 4 + r;
            Ps[wave][(prow * 64 + ni * 16 + l15) ^ ((prow & 7) << 3)] = __float2bfloat16(p);
          }
#pragma unroll
        for (int d = 1; d < 16; d <<= 1)
#pragma unroll
          for (int r = 0; r < 4; r++) rs[r] += __shfl_xor(rs[r], d, 64);
#pragma unroll
        for (int r = 0; r < 4; r++) lrun[r] += rs[r];
      }

      __builtin_amdgcn_s_setprio(1);
#pragma unroll
      for (int kk = 0; kk < 2; kk++) {
        int prow = l15;
        bf16x8 pf = *(const bf16x8*)(Ps[wave] + ((prow * 64 + kk * 32 + l4 * 8) ^ ((prow & 7) << 3)));
#pragma unroll
        for (int ni = 0; ni < 8; ni++) {
          int hd = ni * 16 + l15;
          bf16x8 vf = *(const bf16x8*)(Vs + ((hd * 64 + kk * 32 + l4 * 8) ^ ((hd & 7) << 3)));
          accO[ni] = __builtin_amdgcn_mfma_f32_16x16x32_bf16(pf, vf, accO[ni], 0, 0, 0);
        }
      }
      __builtin_amdgcn_s_setprio(0);

      __syncthreads();
      if (t + 1 < ntiles) STAGE();
    }
#undef TT

    __hip_bfloat16* E = Ks + wave * 2048;
    {
      float inv[4];
#pragma unroll
      for (int r = 0; r < 4; r++) inv[r] = 1.0f / lrun[r];
#pragma unroll
      for (int ni = 0; ni < 8; ni++)
#pragma unroll
        for (int r = 0; r < 4; r++) {
          int row = l4 * 4 + r;
          E[(row * 128 + ni * 16 + l15) ^ ((row & 7) << 3)] =
              __float2bfloat16(accO[ni][r] * inv[r]);
        }
    }
    const long gb = ((long)b * SS + qwb) * 2048 + h * 128;
#pragma unroll
    for (int j = 0; j < 4; j++) {
      int row = j * 4 + l4;
      int c8 = l15 * 8;
      bf16x8 v = *(const bf16x8*)(E + ((row * 128 + c8) ^ ((row & 7) << 3)));
      *(bf16x8*)(aout + gb + (long)row * 2048 + c8) = v;
    }
  }
#undef LOADKV
#undef STAGE
}

extern "C" void kernel_launch(void* const* d_in, const int* in_sizes, int n_in,
                              void* d_out, int out_size, void* d_ws, size_t ws_size,
                              hipStream_t stream) {
  (void)in_sizes; (void)n_in; (void)out_size; (void)ws_size;
  const float* h  = (const float*)d_in[0];
  const float* Wq = (const float*)d_in[1];
  const float* Wk = (const float*)d_in[2];
  const float* Wv = (const float*)d_in[3];
  const float* Wo = (const float*)d_in[4];
  const float* fc = (const float*)d_in[7];
  const float* fs = (const float*)d_in[8];
  const int* pos  = (const int*)d_in[9];
  float* out = (float*)d_out;

  char* ws = (char*)d_ws;
  __hip_bfloat16* hb    = (__hip_bfloat16*)(ws);                 // 33,554,432 B
  __hip_bfloat16* wqkv  = (__hip_bfloat16*)(ws + 33554432);      // 25,165,824 B
  __hip_bfloat16* wo_b  = (__hip_bfloat16*)(ws + 58720256);      //  8,388,608 B
  __hip_bfloat16* qkbuf = (__hip_bfloat16*)(ws + 67108864);      // 67,108,864 B
  __hip_bfloat16* vt    = (__hip_bfloat16*)(ws + 134217728);     // 33,554,432 B
  __hip_bfloat16* aout  = hb;  // alias: hb dead after GEMM1

  convertk<<<16384, 256, 0, stream>>>(h, hb, 4194304);
  convertk<<<4096, 256, 0, stream>>>(Wq, wqkv, 1048576);
  convertk<<<4096, 256, 0, stream>>>(Wk, wqkv + 4194304, 1048576);
  convertk<<<4096, 256, 0, stream>>>(Wv, wqkv + 8388608, 1048576);
  convertk<<<4096, 256, 0, stream>>>(Wo, wo_b, 1048576);

  // QKV projection + fused RoPE: M=8192, N=6144, K=2048  (32x24=768 blocks)
  gemm256<0><<<768, 512, 0, stream>>>(hb, wqkv, qkbuf, vt, nullptr, fc, fs, pos,
                                      8192, 6144, 2048);

  // causal flash attention (balanced, two-stream L2-local, 1024 blocks x 256 threads)
  attn_k<<<1024, 256, 0, stream>>>(qkbuf, vt, aout, pos);

  // output projection: M=8192, N=2048, K=2048 -> fp32 d_out  (32x8=256 blocks)
  gemm256<1><<<256, 512, 0, stream>>>(aout, wo_b, nullptr, nullptr, out, nullptr,
                                      nullptr, nullptr, 8192, 2048, 2048);
}

// Round 10
// 487.493 us; speedup vs baseline: 1.9898x; 1.0931x over previous
//
#include <hip/hip_runtime.h>
#include <hip/hip_bf16.h>

typedef __attribute__((ext_vector_type(8))) short bf16x8;
typedef __attribute__((ext_vector_type(4))) float f32x4;
typedef __attribute__((ext_vector_type(4))) unsigned short u16x4;

#define BB 4
#define SS 2048
#define DD 2048
#define HH 16
#define HDD 128
// QK buffer: [B*S][4096] bf16 (Q cols 0..2047, K cols 2048..4095), RoPE pre-applied
// Vt buffer: [B*H][128][2048] bf16 (V transposed: hd-major, s contiguous)
// Masking sentinels: finite so (masked) - (init) never yields exp2(0)=1.
#define MASKV (-30000.0f)
#define MINIT (-15000.0f)

__device__ __forceinline__ unsigned short f2bf(float f) {
  __hip_bfloat16 b = __float2bfloat16(f);
  return *reinterpret_cast<unsigned short*>(&b);
}
__device__ __forceinline__ void gl_lds16(const void* g, void* l) {
  __builtin_amdgcn_global_load_lds((const __attribute__((address_space(1))) unsigned int*)g,
                                   (__attribute__((address_space(3))) unsigned int*)l, 16, 0, 0);
}

// ---------------- fp32 -> bf16 conversion (vectorized) ----------------
__global__ __launch_bounds__(256) void convertk(const float* __restrict__ src,
                                                __hip_bfloat16* __restrict__ dst, int n4) {
  int i = blockIdx.x * 256 + threadIdx.x;
  if (i >= n4) return;
  f32x4 v = ((const f32x4*)src)[i];
  u16x4 o;
  o[0] = f2bf(v[0]); o[1] = f2bf(v[1]); o[2] = f2bf(v[2]); o[3] = f2bf(v[3]);
  ((u16x4*)dst)[i] = o;
}

// ---------------- 256x256 8-wave B^T GEMM, K-slice phases ----------------
// C[m][n] = sum_k A[m][k] * Bw[n][k].  BK=64, double-buffered 128KB LDS,
// XOR-swizzle (chunk ^= row&7) staged via inverse-swizzled global source
// (global_load_lds writes linearly; round-9 verified: 0 bank conflicts).
// Per K-tile: 2 phases (k-slices of 32). Each phase:
//   {12 ds_read_b128 = af[8]+bg[4] (ALL frags of this k-slice, read exactly once)
//    | stage 2 half-tiles of tile T+1 into buf freed at end of T-1
//    | barrier | 32 MFMA (8x4 full quadrant grid) | barrier}.
// One vmcnt(0) per tile at phase 1. LDS reads = 24/wave/K-tile (minimal; round-9's
// C-quadrant phases read 48 -> LDS pipe was 2x critical path, MfmaUtil capped 34%).
// MODE 0: epilogue -> QK buffer with fused RoPE (n<4096) or Vt (transposed).
// MODE 1: epilogue -> float C row-major [M][N].
template <int MODE>
__global__ __launch_bounds__(512, 1) void gemm256(const __hip_bfloat16* __restrict__ A,
                                                  const __hip_bfloat16* __restrict__ Bw,
                                                  __hip_bfloat16* __restrict__ Cbf,
                                                  __hip_bfloat16* __restrict__ Vt,
                                                  float* __restrict__ Cf,
                                                  const float* __restrict__ fc,
                                                  const float* __restrict__ fs,
                                                  const int* __restrict__ posp,
                                                  int M, int N, int K) {
  __shared__ __hip_bfloat16 As[2][2][128 * 64];  // [buf][half][row*64+col]  64KB
  __shared__ __hip_bfloat16 Bs[2][2][128 * 64];  // 64KB
  const int tid = threadIdx.x;
  const int wid = tid >> 6, lane = tid & 63;
  const int l15 = lane & 15, l4 = lane >> 4;
  const int wm = wid >> 2, wn = wid & 3;  // 2 x 4 wave grid; wave owns 128x64

  const int nbn = N >> 8;
  const int nb = (M >> 8) * nbn;
  const int bid = blockIdx.x;
  const int swz = (bid & 7) * (nb >> 3) + (bid >> 3);  // XCD-contiguous (nb%8==0)
  const int bm = swz / nbn, bn = swz % nbn;

  const int NT = K >> 6;  // K-tiles of 64

// stage half Q (0,1=A halves; 2,3=B halves) of K-offset K0G into buffer BUF.
// 512 threads x 2 loads cover 1024 chunks of 16B; source col pre-swizzled.
#define STAGE_HALF(Q, BUF, K0G)                                                   \
  {                                                                               \
    if ((Q) < 2) {                                                                \
      const long rowb = (long)bm * 256 + (Q) * 128;                               \
      _Pragma("unroll") for (int i = 0; i < 2; i++) {                             \
        int c = i * 512 + tid, rr = c >> 3, jj = (c & 7) ^ (rr & 7);              \
        gl_lds16(A + (rowb + rr) * (long)K + (K0G) + jj * 8,                      \
                 &As[BUF][(Q)][0] + c * 8);                                       \
      }                                                                           \
    } else {                                                                      \
      const long rowb = (long)bn * 256 + ((Q) - 2) * 128;                         \
      _Pragma("unroll") for (int i = 0; i < 2; i++) {                             \
        int c = i * 512 + tid, rr = c >> 3, jj = (c & 7) ^ (rr & 7);              \
        gl_lds16(Bw + (rowb + rr) * (long)K + (K0G) + jj * 8,                     \
                 &Bs[BUF][(Q) - 2][0] + c * 8);                                   \
      }                                                                           \
    }                                                                             \
  }

  f32x4 acc[8][4] = {};

  // prologue: tiles 0 and 1 fully staged
#pragma unroll
  for (int q = 0; q < 4; ++q) STAGE_HALF(q, 0, 0);
#pragma unroll
  for (int q = 0; q < 4; ++q) STAGE_HALF(q, 1, 64);
  __syncthreads();  // vmcnt(0)+lgkm(0)+barrier

  for (int T = 0; T < NT; ++T) {
    const int cur = T & 1;
    const int nxt = cur ^ 1;
    // Buffer rotation proof (round-9, verified): buf[nxt] was consumed by tile
    // T-1 (its trailing barrier passed), so staging tile T+1 into it during
    // tile T is race-free; tile T+1 reads it only after T's vmcnt(0)+barrier.
    const bool do_stage = (T >= 1) && (T + 1 < NT);
    const int k0n = (T + 1) << 6;

#pragma unroll
    for (int k2 = 0; k2 < 2; ++k2) {
      // all fragments of this 32-wide k-slice, each read exactly once
      bf16x8 af[8], bg[4];
#pragma unroll
      for (int mi = 0; mi < 8; mi++) {
        int r = mi * 16 + l15;
        int j = (k2 * 4 + l4) ^ (r & 7);
        af[mi] = *(const bf16x8*)(&As[cur][wm][0] + r * 64 + j * 8);
      }
#pragma unroll
      for (int ni = 0; ni < 4; ni++) {
        int r = (wn & 1) * 64 + ni * 16 + l15;
        int j = (k2 * 4 + l4) ^ (r & 7);
        bg[ni] = *(const bf16x8*)(&Bs[cur][wn >> 1][0] + r * 64 + j * 8);
      }
      if (do_stage) {
        if (k2 == 0) { STAGE_HALF(0, nxt, k0n); STAGE_HALF(1, nxt, k0n); }
        else         { STAGE_HALF(2, nxt, k0n); STAGE_HALF(3, nxt, k0n); }
      }
      __builtin_amdgcn_s_barrier();
      asm volatile("" ::: "memory");
      __builtin_amdgcn_s_setprio(1);
#pragma unroll
      for (int mi = 0; mi < 8; mi++)
#pragma unroll
        for (int ni = 0; ni < 4; ni++)
          acc[mi][ni] = __builtin_amdgcn_mfma_f32_16x16x32_bf16(af[mi], bg[ni],
                                                                acc[mi][ni], 0, 0, 0);
      __builtin_amdgcn_s_setprio(0);
      if (k2 == 1) asm volatile("s_waitcnt vmcnt(0)" ::: "memory");
      __builtin_amdgcn_s_barrier();
      asm volatile("" ::: "memory");
    }
  }
#undef STAGE_HALF

  // ---- epilogue ----
  if (MODE == 0) {
    if (bn * 256 < 4096) {
      const int pos = *posp;
#pragma unroll
      for (int mi = 0; mi < 8; mi++)
#pragma unroll
        for (int ni = 0; ni < 4; ni++) {
          int n = bn * 256 + wn * 64 + ni * 16 + l15;
          int hd = n & 127;
          int ip = hd >> 1;
          bool odd = hd & 1;
#pragma unroll
          for (int r = 0; r < 4; r++) {
            float v = acc[mi][ni][r];
            float p = __shfl_xor(v, 1, 64);
            int m = bm * 256 + wm * 128 + mi * 16 + l4 * 4 + r;
            int s = m & (SS - 1);
            float cv = fc[(long)(pos + s) * 64 + ip];
            float sv = fs[(long)(pos + s) * 64 + ip];
            float out = odd ? (p * sv + v * cv) : (v * cv - p * sv);
            Cbf[(long)m * 4096 + n] = __float2bfloat16(out);
          }
        }
    } else {
#pragma unroll
      for (int mi = 0; mi < 8; mi++)
#pragma unroll
        for (int ni = 0; ni < 4; ni++) {
          int e = bn * 256 + wn * 64 + ni * 16 + l15 - 4096;
          int hh = e >> 7, hd = e & 127;
          int m0 = bm * 256 + wm * 128 + mi * 16 + l4 * 4;
          int b = m0 >> 11, s0 = m0 & (SS - 1);
          u16x4 pk;
#pragma unroll
          for (int r = 0; r < 4; r++) pk[r] = f2bf(acc[mi][ni][r]);
          *(u16x4*)(Vt + (((long)(b * HH + hh) * 128 + hd) * SS + s0)) = pk;
        }
    }
  } else {
#pragma unroll
    for (int mi = 0; mi < 8; mi++)
#pragma unroll
      for (int ni = 0; ni < 4; ni++) {
        int n = bn * 256 + wn * 64 + ni * 16 + l15;
#pragma unroll
        for (int r = 0; r < 4; r++) {
          int m = bm * 256 + wm * 128 + mi * 16 + l4 * 4 + r;
          Cf[(long)m * N + n] = acc[mi][ni][r];
        }
      }
  }
}

// ---------------- causal flash attention (round-8, unchanged) ----------------
__global__ __launch_bounds__(256, 2) void attn_k(const __hip_bfloat16* __restrict__ qk,
                                                 const __hip_bfloat16* __restrict__ vt,
                                                 __hip_bfloat16* __restrict__ aout,
                                                 const int* __restrict__ posp) {
  __shared__ __hip_bfloat16 Ks[64 * 128];
  __shared__ __hip_bfloat16 Vs[128 * 64];
  __shared__ __hip_bfloat16 Ps[4][16 * 64];
  const int pos = *posp;
  const int orig = blockIdx.x;
  const int swz = (orig & 7) * 128 + (orig >> 3);
  const int qp = swz & 15, bh = swz >> 4;
  const int b = bh >> 4, h = bh & 15;
  const int tid = threadIdx.x;
  const int wave = tid >> 6, lane = tid & 63;
  const int l15 = lane & 15, l4 = lane >> 4;

  const long kbase = ((long)b * SS) * 4096 + 2048 + h * 128;
  const long vbase = ((long)bh * 128) * SS;
  const float sc2 = 0.08838834764831845f * 1.4426950408889634f;

  const int s_kr[4] = {(0 * 256 + tid) >> 4, (1 * 256 + tid) >> 4, (2 * 256 + tid) >> 4, (3 * 256 + tid) >> 4};
  const int s_kc = tid & 15;
  const int s_hd[4] = {(0 * 256 + tid) >> 3, (1 * 256 + tid) >> 3, (2 * 256 + tid) >> 3, (3 * 256 + tid) >> 3};
  const int s_vc = tid & 7;

  bf16x8 kreg[4], vreg[4];

#define LOADKV(T)                                                                             \
  {                                                                                           \
    const int kv0_ = (T) * 64;                                                                \
    _Pragma("unroll") for (int i = 0; i < 4; i++) {                                           \
      kreg[i] = *(const bf16x8*)(qk + kbase + (long)(kv0_ + s_kr[i]) * 4096 + s_kc * 8);      \
      vreg[i] = *(const bf16x8*)(vt + vbase + (long)s_hd[i] * SS + kv0_ + s_vc * 8);          \
    }                                                                                         \
  }

#define STAGE()                                                                               \
  {                                                                                           \
    _Pragma("unroll") for (int i = 0; i < 4; i++) {                                           \
      *(bf16x8*)(Ks + ((s_kr[i] * 128 + s_kc * 8) ^ ((s_kr[i] & 7) << 3))) = kreg[i];         \
      *(bf16x8*)(Vs + ((s_hd[i] * 64 + s_vc * 8) ^ ((s_hd[i] & 7) << 3))) = vreg[i];          \
    }                                                                                         \
  }

  for (int half = 0; half < 2; ++half) {
    const int qb = half ? (31 - qp) : qp;
    const int qwb = qb * 64 + wave * 16;

    bf16x8 qf[4];
#pragma unroll
    for (int kk = 0; kk < 4; kk++) {
      long row = (long)b * SS + qwb + l15;
      qf[kk] = *(const bf16x8*)(qk + row * 4096 + h * 128 + kk * 32 + l4 * 8);
    }

    f32x4 accO[8] = {};
    float mrun[4], lrun[4];
#pragma unroll
    for (int r = 0; r < 4; r++) { mrun[r] = MINIT; lrun[r] = 0.f; }

    int ntiles = (pos + qb * 64 + 63) / 64 + 1;
    if (ntiles > SS / 64) ntiles = SS / 64;
#define TT(t) (half ? (ntiles - 1 - (t)) : (t))

    LOADKV(TT(0));
    __syncthreads();
    STAGE();

    for (int t = 0; t < ntiles; ++t) {
      const int kv0 = TT(t) * 64;
      __syncthreads();
      if (t + 1 < ntiles) LOADKV(TT(t + 1));

      f32x4 sfr[4] = {};
      __builtin_amdgcn_s_setprio(1);
#pragma unroll
      for (int ni = 0; ni < 4; ni++) {
        const int key = ni * 16 + l15;
        const int sw = (key & 7) << 3;
#pragma unroll
        for (int kk = 0; kk < 4; kk++) {
          bf16x8 kf = *(const bf16x8*)(Ks + ((key * 128 + kk * 32 + l4 * 8) ^ sw));
          sfr[ni] = __builtin_amdgcn_mfma_f32_16x16x32_bf16(qf[kk], kf, sfr[ni], 0, 0, 0);
        }
      }
      __builtin_amdgcn_s_setprio(0);

      const bool needmask = (kv0 + 63) > (pos + qb * 64);
#pragma unroll
      for (int ni = 0; ni < 4; ni++)
#pragma unroll
        for (int r = 0; r < 4; r++) {
          float v = sfr[ni][r] * sc2;
          if (needmask) {
            int key = kv0 + ni * 16 + l15;
            int q = qwb + l4 * 4 + r;
            if (key > pos + q) v = MASKV;
          }
          sfr[ni][r] = v;
        }

      {
        f32x4 mx = sfr[0];
#pragma unroll
        for (int ni = 1; ni < 4; ni++)
#pragma unroll
          for (int r = 0; r < 4; r++) mx[r] = fmaxf(mx[r], sfr[ni][r]);
#pragma unroll
        for (int d = 1; d < 16; d <<= 1)
#pragma unroll
          for (int r = 0; r < 4; r++) mx[r] = fmaxf(mx[r], __shfl_xor(mx[r], d, 64));

        float growth = mx[0] - mrun[0];
#pragma unroll
        for (int r = 1; r < 4; r++) growth = fmaxf(growth, mx[r] - mrun[r]);
        if (!__all(growth <= 11.0f)) {
          float scal[4];
#pragma unroll
          for (int r = 0; r < 4; r++) {
            float mn = fmaxf(mrun[r], mx[r]);
            scal[r] = exp2f(mrun[r] - mn);
            mrun[r] = mn;
            lrun[r] *= scal[r];
          }
#pragma unroll
          for (int ni = 0; ni < 8; ni++)
#pragma unroll
            for (int r = 0; r < 4; r++) accO[ni][r] *= scal[r];
        }

        f32x4 rs = {0.f, 0.f, 0.f, 0.f};
#pragma unroll
        for (int ni = 0; ni < 4; ni++)
#pragma unroll
          for (int r = 0; r < 4; r++) {
            float p = exp2f(sfr[ni][r] - mrun[r]);
            rs[r] += p;
            int prow = l4 * 4 + r;
            Ps[wave][(prow * 64 + ni * 16 + l15) ^ ((prow & 7) << 3)] = __float2bfloat16(p);
          }
#pragma unroll
        for (int d = 1; d < 16; d <<= 1)
#pragma unroll
          for (int r = 0; r < 4; r++) rs[r] += __shfl_xor(rs[r], d, 64);
#pragma unroll
        for (int r = 0; r < 4; r++) lrun[r] += rs[r];
      }

      __builtin_amdgcn_s_setprio(1);
#pragma unroll
      for (int kk = 0; kk < 2; kk++) {
        int prow = l15;
        bf16x8 pf = *(const bf16x8*)(Ps[wave] + ((prow * 64 + kk * 32 + l4 * 8) ^ ((prow & 7) << 3)));
#pragma unroll
        for (int ni = 0; ni < 8; ni++) {
          int hd = ni * 16 + l15;
          bf16x8 vf = *(const bf16x8*)(Vs + ((hd * 64 + kk * 32 + l4 * 8) ^ ((hd & 7) << 3)));
          accO[ni] = __builtin_amdgcn_mfma_f32_16x16x32_bf16(pf, vf, accO[ni], 0, 0, 0);
        }
      }
      __builtin_amdgcn_s_setprio(0);

      __syncthreads();
      if (t + 1 < ntiles) STAGE();
    }
#undef TT

    __hip_bfloat16* E = Ks + wave * 2048;
    {
      float inv[4];
#pragma unroll
      for (int r = 0; r < 4; r++) inv[r] = 1.0f / lrun[r];
#pragma unroll
      for (int ni = 0; ni < 8; ni++)
#pragma unroll
        for (int r = 0; r < 4; r++) {
          int row = l4 * 4 + r;
          E[(row * 128 + ni * 16 + l15) ^ ((row & 7) << 3)] =
              __float2bfloat16(accO[ni][r] * inv[r]);
        }
    }
    const long gb = ((long)b * SS + qwb) * 2048 + h * 128;
#pragma unroll
    for (int j = 0; j < 4; j++) {
      int row = j * 4 + l4;
      int c8 = l15 * 8;
      bf16x8 v = *(const bf16x8*)(E + ((row * 128 + c8) ^ ((row & 7) << 3)));
      *(bf16x8*)(aout + gb + (long)row * 2048 + c8) = v;
    }
  }
#undef LOADKV
#undef STAGE
}

extern "C" void kernel_launch(void* const* d_in, const int* in_sizes, int n_in,
                              void* d_out, int out_size, void* d_ws, size_t ws_size,
                              hipStream_t stream) {
  (void)in_sizes; (void)n_in; (void)out_size; (void)ws_size;
  const float* h  = (const float*)d_in[0];
  const float* Wq = (const float*)d_in[1];
  const float* Wk = (const float*)d_in[2];
  const float* Wv = (const float*)d_in[3];
  const float* Wo = (const float*)d_in[4];
  const float* fc = (const float*)d_in[7];
  const float* fs = (const float*)d_in[8];
  const int* pos  = (const int*)d_in[9];
  float* out = (float*)d_out;

  char* ws = (char*)d_ws;
  __hip_bfloat16* hb    = (__hip_bfloat16*)(ws);                 // 33,554,432 B
  __hip_bfloat16* wqkv  = (__hip_bfloat16*)(ws + 33554432);      // 25,165,824 B
  __hip_bfloat16* wo_b  = (__hip_bfloat16*)(ws + 58720256);      //  8,388,608 B
  __hip_bfloat16* qkbuf = (__hip_bfloat16*)(ws + 67108864);      // 67,108,864 B
  __hip_bfloat16* vt    = (__hip_bfloat16*)(ws + 134217728);     // 33,554,432 B
  __hip_bfloat16* aout  = hb;  // alias: hb dead after GEMM1

  convertk<<<16384, 256, 0, stream>>>(h, hb, 4194304);
  convertk<<<4096, 256, 0, stream>>>(Wq, wqkv, 1048576);
  convertk<<<4096, 256, 0, stream>>>(Wk, wqkv + 4194304, 1048576);
  convertk<<<4096, 256, 0, stream>>>(Wv, wqkv + 8388608, 1048576);
  convertk<<<4096, 256, 0, stream>>>(Wo, wo_b, 1048576);

  // QKV projection + fused RoPE: M=8192, N=6144, K=2048  (32x24=768 blocks)
  gemm256<0><<<768, 512, 0, stream>>>(hb, wqkv, qkbuf, vt, nullptr, fc, fs, pos,
                                      8192, 6144, 2048);

  // causal flash attention (balanced, two-stream L2-local, 1024 blocks x 256 threads)
  attn_k<<<1024, 256, 0, stream>>>(qkbuf, vt, aout, pos);

  // output projection: M=8192, N=2048, K=2048 -> fp32 d_out  (32x8=256 blocks)
  gemm256<1><<<256, 512, 0, stream>>>(aout, wo_b, nullptr, nullptr, out, nullptr,
                                      nullptr, nullptr, 8192, 2048, 2048);
}